// Round 3
// baseline (163.066 us; speedup 1.0000x reference)
//
#include <hip/hip_runtime.h>
#include <hip/hip_bf16.h>

#define BS   8
#define NREL 16
#define NN   512
#define EMB  256

typedef float f32x4 __attribute__((ext_vector_type(4)));
typedef short s16x8 __attribute__((ext_vector_type(8)));

// f32 -> bf16 bits, round-to-nearest-even
__device__ __forceinline__ unsigned short f2bf_bits(float f) {
    union { float f; unsigned u; } v; v.f = f;
    unsigned r = (v.u + 0x7FFFu + ((v.u >> 16) & 1u)) >> 16;
    return (unsigned short)r;
}

// ---------------------------------------------------------------------------
// K0: transpose W_r[16][256][256] + W_0[256][256] -> wT[17][h][d] bf16
// ---------------------------------------------------------------------------
__global__ __launch_bounds__(256) void k0_transpose(
        const float* __restrict__ Wr, const float* __restrict__ W0,
        unsigned short* __restrict__ wT) {
    __shared__ float tile[32][33];
    int bid = blockIdx.x;
    int rel = bid / 64;          // 0..16
    int t   = bid % 64;
    int d0  = (t & 7) * 32;
    int h0  = (t >> 3) * 32;
    int tx  = threadIdx.x & 31;
    int ty  = threadIdx.x >> 5;  // 0..7
    const float* src = (rel < NREL) ? (Wr + rel * (EMB * EMB)) : W0;
#pragma unroll
    for (int k = 0; k < 4; ++k) {
        int d = d0 + ty + k * 8;
        tile[ty + k * 8][tx] = src[d * EMB + h0 + tx];
    }
    __syncthreads();
#pragma unroll
    for (int k = 0; k < 4; ++k) {
        int h = h0 + ty + k * 8;
        wT[(rel * EMB + h) * EMB + d0 + tx] = f2bf_bits(tile[tx][ty + k * 8]);
    }
}

// ---------------------------------------------------------------------------
// K0b: convert F[8][512][256] f32 -> Fbf bf16 row-major
// ---------------------------------------------------------------------------
__global__ __launch_bounds__(256) void k0b_convF(
        const float* __restrict__ F, unsigned short* __restrict__ Fbf) {
    long i = ((long)blockIdx.x * 256 + threadIdx.x) * 8;
    f32x4 x0 = *(const f32x4*)(F + i);
    f32x4 x1 = *(const f32x4*)(F + i + 4);
    s16x8 v;
    v[0] = (short)f2bf_bits(x0[0]); v[1] = (short)f2bf_bits(x0[1]);
    v[2] = (short)f2bf_bits(x0[2]); v[3] = (short)f2bf_bits(x0[3]);
    v[4] = (short)f2bf_bits(x1[0]); v[5] = (short)f2bf_bits(x1[1]);
    v[6] = (short)f2bf_bits(x1[2]); v[7] = (short)f2bf_bits(x1[3]);
    *(s16x8*)(Fbf + i) = v;
}

// ---------------------------------------------------------------------------
// K1: FW[b][rel][m][h] = sum_d F[b][m][d] * W[rel][d][h]
//   D[h][m] = wT(A) x Fbf(B), MFMA 16x16x32 bf16, all-bf16 operand loads.
//   rel<16  -> FW fragment-major: [(b*16+rel)*64 + m/8][h][m%8] bf16
//   rel==16 -> F2f f32 row-major [b][n][h]
// ---------------------------------------------------------------------------
__global__ __launch_bounds__(256) void k1_fw(
        const unsigned short* __restrict__ Fbf, const unsigned short* __restrict__ wT,
        unsigned short* __restrict__ FW, float* __restrict__ F2f) {
    int bid = blockIdx.x;
    int b   = bid & 7;
    int q   = bid >> 3;          // 0..135
    int rel = q % 17;
    int mt  = q / 17;            // 0..7
    int tid = threadIdx.x;
    int w   = tid >> 6;          // 0..3
    int l   = tid & 63;
    int lg  = l >> 4;            // 0..3
    int lr  = l & 15;

    int h0 = w * 64;             // wave's 64 h-rows (M-dim)
    int m0 = mt * 64;            // block's 64 m-cols (N-dim)

    const unsigned short* wt = wT + rel * (EMB * EMB);
    const unsigned short* Fb = Fbf + (long)b * (NN * EMB);

    f32x4 acc[4][4];
#pragma unroll
    for (int i = 0; i < 4; ++i)
#pragma unroll
        for (int j = 0; j < 4; ++j) acc[i][j] = (f32x4){0.f, 0.f, 0.f, 0.f};

#pragma unroll 2
    for (int kk = 0; kk < EMB; kk += 32) {
        s16x8 afrag[4];
#pragma unroll
        for (int hi = 0; hi < 4; ++hi) {
            int row = h0 + hi * 16 + lr;
            afrag[hi] = *(const s16x8*)(wt + row * EMB + kk + lg * 8);
        }
        s16x8 bfrag[4];
#pragma unroll
        for (int bi = 0; bi < 4; ++bi) {
            int m = m0 + bi * 16 + lr;
            bfrag[bi] = *(const s16x8*)(Fb + m * EMB + kk + lg * 8);
        }
#pragma unroll
        for (int hi = 0; hi < 4; ++hi)
#pragma unroll
            for (int bi = 0; bi < 4; ++bi)
                acc[hi][bi] = __builtin_amdgcn_mfma_f32_16x16x32_bf16(
                    afrag[hi], bfrag[bi], acc[hi][bi], 0, 0, 0);
    }

    // Epilogue: D rows = h, cols = m.  C layout: col = lane&15, row = (lane>>4)*4+j
#pragma unroll
    for (int hi = 0; hi < 4; ++hi) {
#pragma unroll
        for (int bi = 0; bi < 4; ++bi) {
            int m  = m0 + bi * 16 + lr;
            int kg = m >> 3, ko = m & 7;
#pragma unroll
            for (int j = 0; j < 4; ++j) {
                int h = h0 + hi * 16 + lg * 4 + j;
                if (rel < NREL)
                    FW[(long)((b * 16 + rel) * 64 + kg) * 2048 + h * 8 + ko] =
                        f2bf_bits(acc[hi][bi][j]);
                else
                    F2f[((long)b * NN + m) * EMB + h] = acc[hi][bi][j];
            }
        }
    }
}

// ---------------------------------------------------------------------------
// K2: part[rg][b][n][h] = sum_{r in rg(2 rels)} sum_m adj[b][r][n][m]*FW[b][r][m][h]
//   grid 1024 = 8b (XCD-grouped) x 16mt(32 rows) x 8rg(2 rels)
//   block 512 thr = 8 waves (2 wr x 4 wc), wave tile 16 rows x 64 cols, acc[4]
//   distance-1 explicit prefetch of the adjacency (HBM) stream
// ---------------------------------------------------------------------------
__global__ __launch_bounds__(512, 8) void k2_main(
        const float* __restrict__ adj, const unsigned short* __restrict__ FW,
        float* __restrict__ part) {
    int bid = blockIdx.x;
    int b   = bid & 7;
    int t   = bid >> 3;          // 0..127
    int mt  = t & 15;
    int rg  = t >> 4;            // 0..7
    int tid = threadIdx.x;
    int w   = tid >> 6;          // 0..7
    int l   = tid & 63;
    int lg  = l >> 4, lr = l & 15;
    int wr  = w >> 2;            // 0..1
    int wc  = w & 3;             // 0..3

    int nrow = mt * 32 + wr * 16;     // wave's 16 output rows
    int h0   = wc * 64;               // wave's 64 output cols

    f32x4 acc[4];
#pragma unroll
    for (int i = 0; i < 4; ++i) acc[i] = (f32x4){0.f, 0.f, 0.f, 0.f};

    int arow = nrow + lr;
    const float* adj_b = adj + (((long)(b * 16 + rg * 2)) * NN + arow) * NN + lg * 8;
    const unsigned short* fw_b = FW + (long)(b * 16 + rg * 2) * 131072;
    int col0 = (h0 + lr) * 8;

    // flattened (r, kk) loop: it = r*16 + kk/32, 32 iterations
    f32x4 nx0 = *(const f32x4*)adj_b;
    f32x4 nx1 = *(const f32x4*)(adj_b + 4);
#pragma unroll 4
    for (int it = 0; it < 32; ++it) {
        f32x4 x0 = nx0, x1 = nx1;
        if (it < 31) {
            int rn = (it + 1) >> 4, kn = ((it + 1) & 15) * 32;
            const float* pn = adj_b + (long)rn * (NN * NN) + kn;
            nx0 = *(const f32x4*)pn;
            nx1 = *(const f32x4*)(pn + 4);
        }
        int rc = it >> 4, kc = (it & 15) * 32;
        const unsigned short* pk =
            fw_b + (long)rc * 131072 + ((kc >> 3) + lg) * 2048;
        s16x8 b0 = *(const s16x8*)(pk + col0);
        s16x8 b1 = *(const s16x8*)(pk + col0 + 128);
        s16x8 b2 = *(const s16x8*)(pk + col0 + 256);
        s16x8 b3 = *(const s16x8*)(pk + col0 + 384);
        s16x8 a;
        a[0] = (short)f2bf_bits(x0[0]); a[1] = (short)f2bf_bits(x0[1]);
        a[2] = (short)f2bf_bits(x0[2]); a[3] = (short)f2bf_bits(x0[3]);
        a[4] = (short)f2bf_bits(x1[0]); a[5] = (short)f2bf_bits(x1[1]);
        a[6] = (short)f2bf_bits(x1[2]); a[7] = (short)f2bf_bits(x1[3]);
        acc[0] = __builtin_amdgcn_mfma_f32_16x16x32_bf16(a, b0, acc[0], 0, 0, 0);
        acc[1] = __builtin_amdgcn_mfma_f32_16x16x32_bf16(a, b1, acc[1], 0, 0, 0);
        acc[2] = __builtin_amdgcn_mfma_f32_16x16x32_bf16(a, b2, acc[2], 0, 0, 0);
        acc[3] = __builtin_amdgcn_mfma_f32_16x16x32_bf16(a, b3, acc[3], 0, 0, 0);
    }

    // D rows = n (lg*4+j), cols = h (lr). Write f32 partials.
    float* pp = part + ((long)rg * BS + b) * (NN * EMB);
#pragma unroll
    for (int f = 0; f < 4; ++f) {
        int h = h0 + f * 16 + lr;
#pragma unroll
        for (int j = 0; j < 4; ++j) {
            int n = nrow + lg * 4 + j;
            pp[(long)n * EMB + h] = acc[f][j];
        }
    }
}

// ---------------------------------------------------------------------------
// K3: out = relu(sum over 8 rg slices + F2f), vectorized f32x4
// ---------------------------------------------------------------------------
__global__ __launch_bounds__(256) void k3_reduce(
        const float* __restrict__ part, const float* __restrict__ F2f,
        float* __restrict__ out) {
    const long PS = (long)BS * NN * EMB;   // 1,048,576 floats per rg slice
    long i = ((long)blockIdx.x * 256 + threadIdx.x) * 4;
    f32x4 s = *(const f32x4*)(part + i);
#pragma unroll
    for (int rg = 1; rg < 8; ++rg)
        s += *(const f32x4*)(part + i + (long)rg * PS);
    s += *(const f32x4*)(F2f + i);
    f32x4 r;
#pragma unroll
    for (int j = 0; j < 4; ++j) r[j] = s[j] > 0.f ? s[j] : 0.f;
    *(f32x4*)(out + i) = r;
}

// ---------------------------------------------------------------------------
extern "C" void kernel_launch(void* const* d_in, const int* in_sizes, int n_in,
                              void* d_out, int out_size, void* d_ws, size_t ws_size,
                              hipStream_t stream) {
    const float* F   = (const float*)d_in[0];   // [8][512][256]
    const float* adj = (const float*)d_in[1];   // [8][16][512][512]
    const float* Wr  = (const float*)d_in[2];   // [16][256][256]
    const float* W0  = (const float*)d_in[3];   // [256][256]
    float* out = (float*)d_out;                 // [8][512][256]

    unsigned short* wT  = (unsigned short*)d_ws;             // 17*256*256 bf16
    unsigned short* Fbf = wT + 17 * 256 * 256;               // 8*512*256 bf16
    unsigned short* FW  = Fbf + (long)8 * 512 * 256;         // 8*16*64*2048 bf16
    float* F2f  = (float*)(FW + (long)8 * 16 * 64 * 2048);   // 8*512*256 f32
    float* part = F2f + (long)8 * 512 * 256;                 // 8*8*512*256 f32

    k0_transpose<<<17 * 64, 256, 0, stream>>>(Wr, W0, wT);
    k0b_convF<<<512, 256, 0, stream>>>(F, Fbf);
    k1_fw<<<1088, 256, 0, stream>>>(Fbf, wT, FW, F2f);
    k2_main<<<1024, 512, 0, stream>>>(adj, FW, part);
    k3_reduce<<<1024, 256, 0, stream>>>(part, F2f, out);
}

// Round 4
// 114.285 us; speedup vs baseline: 1.4268x; 1.4268x over previous
//
#include <hip/hip_runtime.h>
#include <hip/hip_bf16.h>

#define BS   8
#define NREL 16
#define NN   512
#define EMB  256

typedef float f32x4 __attribute__((ext_vector_type(4)));
typedef short s16x8 __attribute__((ext_vector_type(8)));

#define GLOBAL_AS __attribute__((address_space(1)))
#define LDS_AS    __attribute__((address_space(3)))

// f32 -> bf16 bits, round-to-nearest-even
__device__ __forceinline__ unsigned short f2bf_bits(float f) {
    union { float f; unsigned u; } v; v.f = f;
    unsigned r = (v.u + 0x7FFFu + ((v.u >> 16) & 1u)) >> 16;
    return (unsigned short)r;
}

// async global->LDS, 16 bytes per lane
__device__ __forceinline__ void stage16(const void* g, void* l) {
    __builtin_amdgcn_global_load_lds((const GLOBAL_AS unsigned int*)g,
                                     (LDS_AS unsigned int*)l, 16, 0, 0);
}

// ---------------------------------------------------------------------------
// K0: transpose W_r[16][256][256] + W_0[256][256] -> wT[17][h][d] bf16
// ---------------------------------------------------------------------------
__global__ __launch_bounds__(256) void k0_transpose(
        const float* __restrict__ Wr, const float* __restrict__ W0,
        unsigned short* __restrict__ wT) {
    __shared__ float tile[32][33];
    int bid = blockIdx.x;
    int rel = bid / 64;          // 0..16
    int t   = bid % 64;
    int d0  = (t & 7) * 32;
    int h0  = (t >> 3) * 32;
    int tx  = threadIdx.x & 31;
    int ty  = threadIdx.x >> 5;  // 0..7
    const float* src = (rel < NREL) ? (Wr + rel * (EMB * EMB)) : W0;
#pragma unroll
    for (int k = 0; k < 4; ++k) {
        int d = d0 + ty + k * 8;
        tile[ty + k * 8][tx] = src[d * EMB + h0 + tx];
    }
    __syncthreads();
#pragma unroll
    for (int k = 0; k < 4; ++k) {
        int h = h0 + ty + k * 8;
        wT[(rel * EMB + h) * EMB + d0 + tx] = f2bf_bits(tile[tx][ty + k * 8]);
    }
}

// ---------------------------------------------------------------------------
// K0b: convert F[8][512][256] f32 -> Fbf bf16 row-major
// ---------------------------------------------------------------------------
__global__ __launch_bounds__(256) void k0b_convF(
        const float* __restrict__ F, unsigned short* __restrict__ Fbf) {
    long i = ((long)blockIdx.x * 256 + threadIdx.x) * 8;
    f32x4 x0 = *(const f32x4*)(F + i);
    f32x4 x1 = *(const f32x4*)(F + i + 4);
    s16x8 v;
    v[0] = (short)f2bf_bits(x0[0]); v[1] = (short)f2bf_bits(x0[1]);
    v[2] = (short)f2bf_bits(x0[2]); v[3] = (short)f2bf_bits(x0[3]);
    v[4] = (short)f2bf_bits(x1[0]); v[5] = (short)f2bf_bits(x1[1]);
    v[6] = (short)f2bf_bits(x1[2]); v[7] = (short)f2bf_bits(x1[3]);
    *(s16x8*)(Fbf + i) = v;
}

// ---------------------------------------------------------------------------
// K1: FW[b][rel][m][h] = sum_d F[b][m][d] * W[rel][d][h]
//   D[h][m] = wT(A) x Fbf(B), MFMA 16x16x32 bf16, all-bf16 operand loads.
//   rel<16  -> FW fragment-major: [(b*16+rel)*64 + m/8][h][m%8] bf16
//   rel==16 -> F2f f32 row-major [b][n][h]
// ---------------------------------------------------------------------------
__global__ __launch_bounds__(256) void k1_fw(
        const unsigned short* __restrict__ Fbf, const unsigned short* __restrict__ wT,
        unsigned short* __restrict__ FW, float* __restrict__ F2f) {
    int bid = blockIdx.x;
    int b   = bid & 7;
    int q   = bid >> 3;          // 0..135
    int rel = q % 17;
    int mt  = q / 17;            // 0..7
    int tid = threadIdx.x;
    int w   = tid >> 6;          // 0..3
    int l   = tid & 63;
    int lg  = l >> 4;            // 0..3
    int lr  = l & 15;

    int h0 = w * 64;             // wave's 64 h-rows (M-dim)
    int m0 = mt * 64;            // block's 64 m-cols (N-dim)

    const unsigned short* wt = wT + rel * (EMB * EMB);
    const unsigned short* Fb = Fbf + (long)b * (NN * EMB);

    f32x4 acc[4][4];
#pragma unroll
    for (int i = 0; i < 4; ++i)
#pragma unroll
        for (int j = 0; j < 4; ++j) acc[i][j] = (f32x4){0.f, 0.f, 0.f, 0.f};

#pragma unroll 2
    for (int kk = 0; kk < EMB; kk += 32) {
        s16x8 afrag[4];
#pragma unroll
        for (int hi = 0; hi < 4; ++hi) {
            int row = h0 + hi * 16 + lr;
            afrag[hi] = *(const s16x8*)(wt + row * EMB + kk + lg * 8);
        }
        s16x8 bfrag[4];
#pragma unroll
        for (int bi = 0; bi < 4; ++bi) {
            int m = m0 + bi * 16 + lr;
            bfrag[bi] = *(const s16x8*)(Fb + m * EMB + kk + lg * 8);
        }
#pragma unroll
        for (int hi = 0; hi < 4; ++hi)
#pragma unroll
            for (int bi = 0; bi < 4; ++bi)
                acc[hi][bi] = __builtin_amdgcn_mfma_f32_16x16x32_bf16(
                    afrag[hi], bfrag[bi], acc[hi][bi], 0, 0, 0);
    }

    // Epilogue: D rows = h, cols = m.  C layout: col = lane&15, row = (lane>>4)*4+j
#pragma unroll
    for (int hi = 0; hi < 4; ++hi) {
#pragma unroll
        for (int bi = 0; bi < 4; ++bi) {
            int m  = m0 + bi * 16 + lr;
            int kg = m >> 3, ko = m & 7;
#pragma unroll
            for (int j = 0; j < 4; ++j) {
                int h = h0 + hi * 16 + lg * 4 + j;
                if (rel < NREL)
                    FW[(long)((b * 16 + rel) * 64 + kg) * 2048 + h * 8 + ko] =
                        f2bf_bits(acc[hi][bi][j]);
                else
                    F2f[((long)b * NN + m) * EMB + h] = acc[hi][bi][j];
            }
        }
    }
}

// ---------------------------------------------------------------------------
// K2: part[rg][b][n][h] = sum_{r in rg(2 rels)} sum_m adj[b][r][n][m]*FW[b][r][m][h]
//   grid 512 = 8b (XCD-grouped) x 8nt(64 rows) x 8rg(2 rels)
//   block 512 thr = 8 waves (4 wr x 2 wc), wave tile 16 rows x 128 cols, acc[8]
//   FW staged to LDS (double-buffered, global_load_lds w16); adjacency dist-1
//   register prefetch. One __syncthreads per K-step.
// ---------------------------------------------------------------------------
__global__ __launch_bounds__(512, 4) void k2_main(
        const float* __restrict__ adj, const unsigned short* __restrict__ FW,
        float* __restrict__ part) {
    __shared__ unsigned short Blds[2][8192];   // [buf][kg(4)][h(256)][ko(8)] = 16KB each
    int bid = blockIdx.x;
    int b   = bid & 7;
    int t   = bid >> 3;          // 0..63
    int nt  = t & 7;
    int rg  = t >> 3;            // 0..7
    int tid = threadIdx.x;
    int w   = tid >> 6;          // 0..7
    int l   = tid & 63;
    int lg  = l >> 4, lr = l & 15;
    int wr  = w >> 1;            // 0..3
    int wc  = w & 1;             // 0..1

    int nrow = nt * 64 + wr * 16;     // wave's 16 output rows
    int h0   = wc * 128;              // wave's 128 output cols

    f32x4 acc[8];
#pragma unroll
    for (int i = 0; i < 8; ++i) acc[i] = (f32x4){0.f, 0.f, 0.f, 0.f};

    const float* adj_base =
        adj + (((long)(b * 16 + rg * 2)) * NN + nrow + lr) * NN + lg * 8;
    const unsigned short* fw_b = FW + (long)(b * 16 + rg * 2) * 131072;

    // prologue: stage slice 0, load adjacency slice 0 into regs
    {
        const unsigned short* src = fw_b + tid * 8;
        unsigned short* dst = &Blds[0][tid * 8];
        stage16(src, dst);
        stage16(src + 4096, dst + 4096);
    }
    f32x4 x0 = *(const f32x4*)adj_base;
    f32x4 x1 = *(const f32x4*)(adj_base + 4);
    __syncthreads();   // slice 0 resident

    int cur = 0;
    for (int s = 0; s < 32; ++s) {
        // issue next slice stage + adjacency prefetch FIRST (hide under compute)
        f32x4 nx0 = x0, nx1 = x1;
        if (s < 31) {
            int sn = s + 1;
            long soff = (long)(sn >> 4) * 131072 + (sn & 15) * 8192;
            const unsigned short* src = fw_b + soff + tid * 8;
            unsigned short* dst = &Blds[cur ^ 1][tid * 8];
            stage16(src, dst);
            stage16(src + 4096, dst + 4096);
            const float* pn = adj_base + (long)(sn >> 4) * (NN * NN) + (sn & 15) * 32;
            nx0 = *(const f32x4*)pn;
            nx1 = *(const f32x4*)(pn + 4);
        }
        // convert adjacency regs -> bf16 A-frag
        s16x8 a;
        a[0] = (short)f2bf_bits(x0[0]); a[1] = (short)f2bf_bits(x0[1]);
        a[2] = (short)f2bf_bits(x0[2]); a[3] = (short)f2bf_bits(x0[3]);
        a[4] = (short)f2bf_bits(x1[0]); a[5] = (short)f2bf_bits(x1[1]);
        a[6] = (short)f2bf_bits(x1[2]); a[7] = (short)f2bf_bits(x1[3]);
        // B-frags from LDS
        const unsigned short* bl = &Blds[cur][lg * 2048];
        s16x8 bf[8];
#pragma unroll
        for (int f = 0; f < 8; ++f)
            bf[f] = *(const s16x8*)(bl + (h0 + f * 16 + lr) * 8);
#pragma unroll
        for (int f = 0; f < 8; ++f)
            acc[f] = __builtin_amdgcn_mfma_f32_16x16x32_bf16(a, bf[f], acc[f], 0, 0, 0);
        __syncthreads();   // drains stage(s+1); protects buf reuse
        x0 = nx0; x1 = nx1; cur ^= 1;
    }

    // D rows = n (lg*4+j), cols = h (lr). Write f32 partials.
    float* pp = part + ((long)rg * BS + b) * (NN * EMB);
#pragma unroll
    for (int f = 0; f < 8; ++f) {
        int h = h0 + f * 16 + lr;
#pragma unroll
        for (int j = 0; j < 4; ++j) {
            int n = nrow + lg * 4 + j;
            pp[(long)n * EMB + h] = acc[f][j];
        }
    }
}

// ---------------------------------------------------------------------------
// K3: out = relu(sum over 8 rg slices + F2f), vectorized f32x4
// ---------------------------------------------------------------------------
__global__ __launch_bounds__(256) void k3_reduce(
        const float* __restrict__ part, const float* __restrict__ F2f,
        float* __restrict__ out) {
    const long PS = (long)BS * NN * EMB;   // 1,048,576 floats per rg slice
    long i = ((long)blockIdx.x * 256 + threadIdx.x) * 4;
    f32x4 s = *(const f32x4*)(part + i);
#pragma unroll
    for (int rg = 1; rg < 8; ++rg)
        s += *(const f32x4*)(part + i + (long)rg * PS);
    s += *(const f32x4*)(F2f + i);
    f32x4 r;
#pragma unroll
    for (int j = 0; j < 4; ++j) r[j] = s[j] > 0.f ? s[j] : 0.f;
    *(f32x4*)(out + i) = r;
}

// ---------------------------------------------------------------------------
extern "C" void kernel_launch(void* const* d_in, const int* in_sizes, int n_in,
                              void* d_out, int out_size, void* d_ws, size_t ws_size,
                              hipStream_t stream) {
    const float* F   = (const float*)d_in[0];   // [8][512][256]
    const float* adj = (const float*)d_in[1];   // [8][16][512][512]
    const float* Wr  = (const float*)d_in[2];   // [16][256][256]
    const float* W0  = (const float*)d_in[3];   // [256][256]
    float* out = (float*)d_out;                 // [8][512][256]

    unsigned short* wT  = (unsigned short*)d_ws;             // 17*256*256 bf16
    unsigned short* Fbf = wT + 17 * 256 * 256;               // 8*512*256 bf16
    unsigned short* FW  = Fbf + (long)8 * 512 * 256;         // 8*16*64*2048 bf16
    float* F2f  = (float*)(FW + (long)8 * 16 * 64 * 2048);   // 8*512*256 f32
    float* part = F2f + (long)8 * 512 * 256;                 // 8*8*512*256 f32

    k0_transpose<<<17 * 64, 256, 0, stream>>>(Wr, W0, wT);
    k0b_convF<<<512, 256, 0, stream>>>(F, Fbf);
    k1_fw<<<1088, 256, 0, stream>>>(Fbf, wT, FW, F2f);
    k2_main<<<512, 512, 0, stream>>>(adj, FW, part);
    k3_reduce<<<1024, 256, 0, stream>>>(part, F2f, out);
}

// Round 6
// 113.820 us; speedup vs baseline: 1.4327x; 1.0041x over previous
//
#include <hip/hip_runtime.h>
#include <hip/hip_bf16.h>

#define BS   8
#define NREL 16
#define NN   512
#define EMB  256

typedef float f32x4 __attribute__((ext_vector_type(4)));
typedef short s16x8 __attribute__((ext_vector_type(8)));

// f32 -> bf16 bits, round-to-nearest-even
__device__ __forceinline__ unsigned short f2bf_bits(float f) {
    union { float f; unsigned u; } v; v.f = f;
    unsigned r = (v.u + 0x7FFFu + ((v.u >> 16) & 1u)) >> 16;
    return (unsigned short)r;
}

// ---------------------------------------------------------------------------
// K0: transpose W_r[16][256][256] + W_0[256][256] -> wT[17][h][d] bf16
// ---------------------------------------------------------------------------
__global__ __launch_bounds__(256) void k0_transpose(
        const float* __restrict__ Wr, const float* __restrict__ W0,
        unsigned short* __restrict__ wT) {
    __shared__ float tile[32][33];
    int bid = blockIdx.x;
    int rel = bid / 64;          // 0..16
    int t   = bid % 64;
    int d0  = (t & 7) * 32;
    int h0  = (t >> 3) * 32;
    int tx  = threadIdx.x & 31;
    int ty  = threadIdx.x >> 5;  // 0..7
    const float* src = (rel < NREL) ? (Wr + rel * (EMB * EMB)) : W0;
#pragma unroll
    for (int k = 0; k < 4; ++k) {
        int d = d0 + ty + k * 8;
        tile[ty + k * 8][tx] = src[d * EMB + h0 + tx];
    }
    __syncthreads();
#pragma unroll
    for (int k = 0; k < 4; ++k) {
        int h = h0 + ty + k * 8;
        wT[(rel * EMB + h) * EMB + d0 + tx] = f2bf_bits(tile[tx][ty + k * 8]);
    }
}

// ---------------------------------------------------------------------------
// K0b: convert F[8][512][256] f32 -> Fbf bf16 row-major
// ---------------------------------------------------------------------------
__global__ __launch_bounds__(256) void k0b_convF(
        const float* __restrict__ F, unsigned short* __restrict__ Fbf) {
    long i = ((long)blockIdx.x * 256 + threadIdx.x) * 8;
    f32x4 x0 = *(const f32x4*)(F + i);
    f32x4 x1 = *(const f32x4*)(F + i + 4);
    s16x8 v;
    v[0] = (short)f2bf_bits(x0[0]); v[1] = (short)f2bf_bits(x0[1]);
    v[2] = (short)f2bf_bits(x0[2]); v[3] = (short)f2bf_bits(x0[3]);
    v[4] = (short)f2bf_bits(x1[0]); v[5] = (short)f2bf_bits(x1[1]);
    v[6] = (short)f2bf_bits(x1[2]); v[7] = (short)f2bf_bits(x1[3]);
    *(s16x8*)(Fbf + i) = v;
}

// ---------------------------------------------------------------------------
// K1: FW[b][rel][m][h] = sum_d F[b][m][d] * W[rel][d][h]
//   D[h][m] = wT(A) x Fbf(B), MFMA 16x16x32 bf16, all-bf16 operand loads.
//   rel<16  -> FW fragment-major: [(b*16+rel)*64 + m/8][h][m%8] bf16
//   rel==16 -> F2f f32 row-major [b][n][h]
// ---------------------------------------------------------------------------
__global__ __launch_bounds__(256) void k1_fw(
        const unsigned short* __restrict__ Fbf, const unsigned short* __restrict__ wT,
        unsigned short* __restrict__ FW, float* __restrict__ F2f) {
    int bid = blockIdx.x;
    int b   = bid & 7;
    int q   = bid >> 3;          // 0..135
    int rel = q % 17;
    int mt  = q / 17;            // 0..7
    int tid = threadIdx.x;
    int w   = tid >> 6;          // 0..3
    int l   = tid & 63;
    int lg  = l >> 4;            // 0..3
    int lr  = l & 15;

    int h0 = w * 64;             // wave's 64 h-rows (M-dim)
    int m0 = mt * 64;            // block's 64 m-cols (N-dim)

    const unsigned short* wt = wT + rel * (EMB * EMB);
    const unsigned short* Fb = Fbf + (long)b * (NN * EMB);

    f32x4 acc[4][4];
#pragma unroll
    for (int i = 0; i < 4; ++i)
#pragma unroll
        for (int j = 0; j < 4; ++j) acc[i][j] = (f32x4){0.f, 0.f, 0.f, 0.f};

#pragma unroll 2
    for (int kk = 0; kk < EMB; kk += 32) {
        s16x8 afrag[4];
#pragma unroll
        for (int hi = 0; hi < 4; ++hi) {
            int row = h0 + hi * 16 + lr;
            afrag[hi] = *(const s16x8*)(wt + row * EMB + kk + lg * 8);
        }
        s16x8 bfrag[4];
#pragma unroll
        for (int bi = 0; bi < 4; ++bi) {
            int m = m0 + bi * 16 + lr;
            bfrag[bi] = *(const s16x8*)(Fb + m * EMB + kk + lg * 8);
        }
#pragma unroll
        for (int hi = 0; hi < 4; ++hi)
#pragma unroll
            for (int bi = 0; bi < 4; ++bi)
                acc[hi][bi] = __builtin_amdgcn_mfma_f32_16x16x32_bf16(
                    afrag[hi], bfrag[bi], acc[hi][bi], 0, 0, 0);
    }

    // Epilogue: D rows = h, cols = m.  C layout: col = lane&15, row = (lane>>4)*4+j
#pragma unroll
    for (int hi = 0; hi < 4; ++hi) {
#pragma unroll
        for (int bi = 0; bi < 4; ++bi) {
            int m  = m0 + bi * 16 + lr;
            int kg = m >> 3, ko = m & 7;
#pragma unroll
            for (int j = 0; j < 4; ++j) {
                int h = h0 + hi * 16 + lg * 4 + j;
                if (rel < NREL)
                    FW[(long)((b * 16 + rel) * 64 + kg) * 2048 + h * 8 + ko] =
                        f2bf_bits(acc[hi][bi][j]);
                else
                    F2f[((long)b * NN + m) * EMB + h] = acc[hi][bi][j];
            }
        }
    }
}

// ---------------------------------------------------------------------------
// K2: part[rg][b][n][h] = sum_{r in rg(2 rels)} sum_m adj[b][r][n][m]*FW[b][r][m][h]
//   grid 512 = 8b (XCD-grouped) x 8nt(64 rows) x 8rg(2 rels)
//   block 512 thr = 8 waves (4 wr x 2 wc), wave tile 16 rows x 128 cols, acc[8]
//   T14 reg-staged pipeline (all deps compiler-visible, homogeneous VMEM):
//     iter s: issue global loads slice s+2 (FW->reg, adj->reg, distance 2)
//             compute slice s from LDS buf[s&1] + adj reg ring
//             ds_write FW slice s+1 regs -> buf[(s+1)&1]
//             lgkmcnt(0); raw s_barrier (no vmcnt(0) drain anywhere in loop)
// ---------------------------------------------------------------------------
__global__ __launch_bounds__(512, 4) void k2_main(
        const float* __restrict__ adj, const unsigned short* __restrict__ FW,
        float* __restrict__ part) {
    __shared__ unsigned short Blds[2][8192];   // 2 x 16KB double buffer
    int bid = blockIdx.x;
    int b   = bid & 7;
    int t   = bid >> 3;          // 0..63
    int nt  = t & 7;
    int rg  = t >> 3;            // 0..7
    int tid = threadIdx.x;
    int w   = tid >> 6;          // 0..7
    int l   = tid & 63;
    int lg  = l >> 4, lr = l & 15;
    int wr  = w >> 1;            // 0..3
    int wc  = w & 1;             // 0..1

    int nrow = nt * 64 + wr * 16;     // wave's 16 output rows
    int h0   = wc * 128;              // wave's 128 output cols

    f32x4 acc[8];
#pragma unroll
    for (int i = 0; i < 8; ++i) acc[i] = (f32x4){0.f, 0.f, 0.f, 0.f};

    const float* adj_base =
        adj + (((long)(b * 16 + rg * 2)) * NN + nrow + lr) * NN + lg * 8;
    const unsigned short* fw_t = FW + (long)(b * 16 + rg * 2) * 131072 + tid * 8;

    // register rings: adjacency slot = slice&3, FW staging slot = slice&1
    f32x4 ax[4], ay[4];
    s16x8 fw0[2], fw1[2];

    // ---- prologue: issue slice 0 and slice 1 loads, write buf0, barrier
    fw0[0] = *(const s16x8*)(fw_t);
    fw1[0] = *(const s16x8*)(fw_t + 4096);
    ax[0]  = *(const f32x4*)(adj_base);
    ay[0]  = *(const f32x4*)(adj_base + 4);
    fw0[1] = *(const s16x8*)(fw_t + 8192);
    fw1[1] = *(const s16x8*)(fw_t + 8192 + 4096);
    ax[1]  = *(const f32x4*)(adj_base + 32);
    ay[1]  = *(const f32x4*)(adj_base + 36);
    *(s16x8*)(&Blds[0][tid * 8])        = fw0[0];   // compiler waits fw0[0]/fw1[0]
    *(s16x8*)(&Blds[0][tid * 8 + 4096]) = fw1[0];
    asm volatile("s_waitcnt lgkmcnt(0)" ::: "memory");
    __builtin_amdgcn_sched_barrier(0);
    __builtin_amdgcn_s_barrier();
    asm volatile("" ::: "memory");

#pragma unroll
    for (int s = 0; s < 32; ++s) {
        // 1. issue slice s+2 loads (FW + adjacency), distance-2 prefetch
        if (s + 2 < 32) {
            int sn = s + 2;
            const unsigned short* fsrc =
                fw_t + (long)(sn >> 4) * 131072 + (sn & 15) * 8192;
            fw0[sn & 1] = *(const s16x8*)(fsrc);
            fw1[sn & 1] = *(const s16x8*)(fsrc + 4096);
            const float* pn =
                adj_base + (long)(sn >> 4) * (NN * NN) + (sn & 15) * 32;
            ax[sn & 3] = *(const f32x4*)pn;
            ay[sn & 3] = *(const f32x4*)(pn + 4);
        }

        // 2. compute slice s: A-frag from reg ring, B-frags from buf[s&1]
        f32x4 x0 = ax[s & 3], x1 = ay[s & 3];
        s16x8 a;
        a[0] = (short)f2bf_bits(x0[0]); a[1] = (short)f2bf_bits(x0[1]);
        a[2] = (short)f2bf_bits(x0[2]); a[3] = (short)f2bf_bits(x0[3]);
        a[4] = (short)f2bf_bits(x1[0]); a[5] = (short)f2bf_bits(x1[1]);
        a[6] = (short)f2bf_bits(x1[2]); a[7] = (short)f2bf_bits(x1[3]);
        const unsigned short* bl = &Blds[s & 1][lg * 2048];
#pragma unroll
        for (int f = 0; f < 8; ++f) {
            s16x8 bf = *(const s16x8*)(bl + (h0 + f * 16 + lr) * 8);
            acc[f] = __builtin_amdgcn_mfma_f32_16x16x32_bf16(a, bf, acc[f], 0, 0, 0);
        }
        asm volatile("" ::: "memory");   // ds_reads above, ds_writes below

        // 3. stage slice s+1 into buf[(s+1)&1]; make visible; barrier
        if (s + 1 < 32) {
            *(s16x8*)(&Blds[(s + 1) & 1][tid * 8])        = fw0[(s + 1) & 1];
            *(s16x8*)(&Blds[(s + 1) & 1][tid * 8 + 4096]) = fw1[(s + 1) & 1];
            asm volatile("s_waitcnt lgkmcnt(0)" ::: "memory");
            __builtin_amdgcn_sched_barrier(0);
            __builtin_amdgcn_s_barrier();
            asm volatile("" ::: "memory");
        }
    }

    // D rows = n (lg*4+j), cols = h (lr). Write f32 partials.
    float* pp = part + ((long)rg * BS + b) * (NN * EMB);
#pragma unroll
    for (int f = 0; f < 8; ++f) {
        int h = h0 + f * 16 + lr;
#pragma unroll
        for (int j = 0; j < 4; ++j) {
            int n = nrow + lg * 4 + j;
            pp[(long)n * EMB + h] = acc[f][j];
        }
    }
}

// ---------------------------------------------------------------------------
// K3: out = relu(sum over 8 rg slices + F2f), vectorized f32x4
// ---------------------------------------------------------------------------
__global__ __launch_bounds__(256) void k3_reduce(
        const float* __restrict__ part, const float* __restrict__ F2f,
        float* __restrict__ out) {
    const long PS = (long)BS * NN * EMB;   // 1,048,576 floats per rg slice
    long i = ((long)blockIdx.x * 256 + threadIdx.x) * 4;
    f32x4 s = *(const f32x4*)(part + i);
#pragma unroll
    for (int rg = 1; rg < 8; ++rg)
        s += *(const f32x4*)(part + i + (long)rg * PS);
    s += *(const f32x4*)(F2f + i);
    f32x4 r;
#pragma unroll
    for (int j = 0; j < 4; ++j) r[j] = s[j] > 0.f ? s[j] : 0.f;
    *(f32x4*)(out + i) = r;
}

// ---------------------------------------------------------------------------
extern "C" void kernel_launch(void* const* d_in, const int* in_sizes, int n_in,
                              void* d_out, int out_size, void* d_ws, size_t ws_size,
                              hipStream_t stream) {
    const float* F   = (const float*)d_in[0];   // [8][512][256]
    const float* adj = (const float*)d_in[1];   // [8][16][512][512]
    const float* Wr  = (const float*)d_in[2];   // [16][256][256]
    const float* W0  = (const float*)d_in[3];   // [256][256]
    float* out = (float*)d_out;                 // [8][512][256]

    unsigned short* wT  = (unsigned short*)d_ws;             // 17*256*256 bf16
    unsigned short* Fbf = wT + 17 * 256 * 256;               // 8*512*256 bf16
    unsigned short* FW  = Fbf + (long)8 * 512 * 256;         // 8*16*64*2048 bf16
    float* F2f  = (float*)(FW + (long)8 * 16 * 64 * 2048);   // 8*512*256 f32
    float* part = F2f + (long)8 * 512 * 256;                 // 8*8*512*256 f32

    k0_transpose<<<17 * 64, 256, 0, stream>>>(Wr, W0, wT);
    k0b_convF<<<512, 256, 0, stream>>>(F, Fbf);
    k1_fw<<<1088, 256, 0, stream>>>(Fbf, wT, FW, F2f);
    k2_main<<<512, 512, 0, stream>>>(adj, FW, part);
    k3_reduce<<<1024, 256, 0, stream>>>(part, F2f, out);
}